// Round 4
// baseline (244.927 us; speedup 1.0000x reference)
//
#include <hip/hip_runtime.h>
#include <hip/hip_bf16.h>
#include <cstdint>
#include <cstddef>

#define B_ 4
#define L_ 2048
#define H_ 16
#define D_ 64
#define BH_ (B_*H_)

typedef __attribute__((ext_vector_type(8))) short short8;
typedef __attribute__((ext_vector_type(4))) short short4_t;
typedef __attribute__((ext_vector_type(4))) float f32x4;

__device__ __forceinline__ short f2bf(float x) {
    union { float f; unsigned u; } v; v.f = x;
    unsigned r = v.u + 0x7fffu + ((v.u >> 16) & 1u);
    return (short)(r >> 16);
}

__device__ __forceinline__ short8 pack8(float4 a, float4 b, float sc) {
    short8 t;
    t[0] = f2bf(a.x * sc); t[1] = f2bf(a.y * sc);
    t[2] = f2bf(a.z * sc); t[3] = f2bf(a.w * sc);
    t[4] = f2bf(b.x * sc); t[5] = f2bf(b.y * sc);
    t[6] = f2bf(b.z * sc); t[7] = f2bf(b.w * sc);
    return t;
}

__device__ __forceinline__ float fast_exp2(float x) {
#if __has_builtin(__builtin_amdgcn_exp2f)
    return __builtin_amdgcn_exp2f(x);
#else
    return exp2f(x);
#endif
}

// async global->LDS, 16B per lane; LDS dest is wave-uniform base + lane*16
__device__ __forceinline__ void gld16(const void* g, void* l) {
    __builtin_amdgcn_global_load_lds(
        (const __attribute__((address_space(1))) void*)g,
        (__attribute__((address_space(3))) void*)l, 16, 0, 0);
}

// ---------------- pre-pass: K -> bf16 [bh][s][d], V -> bf16 transposed [bh][d][s]
__global__ __launch_bounds__(256) void prepack(
    const float* __restrict__ K, const float* __restrict__ V,
    short* __restrict__ Kb, short* __restrict__ Vt)
{
    const int blk = blockIdx.x;          // 64 bh x 32 s-tiles
    const int bh  = blk >> 5;
    const int s0  = (blk & 31) * 64;
    const int b   = bh >> 4, h = bh & 15;
    const int t   = threadIdx.x;
    __shared__ short Ls[64 * 72];

#pragma unroll
    for (int half = 0; half < 2; ++half) {
        const int sl = (t >> 3) + half * 32;
        const int dc = (t & 7) * 8;
        const size_t src_off = ((size_t)((b * L_ + s0 + sl) * H_ + h)) * D_ + dc;
        float4 f0 = *(const float4*)(K + src_off);
        float4 f1 = *(const float4*)(K + src_off + 4);
        *(short8*)&Kb[((size_t)bh * L_ + s0 + sl) * D_ + dc] = pack8(f0, f1, 1.0f);
        float4 g0 = *(const float4*)(V + src_off);
        float4 g1 = *(const float4*)(V + src_off + 4);
        *(short8*)&Ls[sl * 72 + dc] = pack8(g0, g1, 1.0f);
    }
    __syncthreads();
    const int d  = t >> 2;
    const int sc = (t & 3) * 16;
    short8 o0, o1;
#pragma unroll
    for (int j = 0; j < 8; ++j) o0[j] = Ls[(sc + j) * 72 + d];
#pragma unroll
    for (int j = 0; j < 8; ++j) o1[j] = Ls[(sc + 8 + j) * 72 + d];
    short* dst = Vt + ((size_t)bh * D_ + d) * L_ + s0 + sc;
    *(short8*)dst = o0;
    *(short8*)(dst + 8) = o1;
}

// ---------------- main kernel: paired q-tiles (i, 31-i), dbuf global_load_lds staging
// R4: R0 structure + early V-fragment loads (latency off the P critical path)
//     + s_setprio(1) around QK and PV MFMA clusters (T5).
__global__ __launch_bounds__(256, 4) void fa_fwd2(
    const float* __restrict__ Q, const short* __restrict__ Kb,
    const short* __restrict__ Vt, float* __restrict__ O)
{
    const int tid  = threadIdx.x;
    const int wave = tid >> 6;
    const int lane = tid & 63;
    const int quad = lane >> 4;
    const int l16  = lane & 15;

    const int blk  = blockIdx.x;
    const int xcd  = blk & 7;
    const int slot = blk >> 3;           // 0..127
    const int bh   = xcd * 8 + (slot & 7);
    const int ip   = slot >> 3;          // 0..15 pair index (mixed across a CU's blocks)
    const int b    = bh >> 4;
    const int h    = bh & 15;
    const int qtA  = ip;                 // short q-tile
    const int qtB  = 31 - ip;            // long q-tile
    const int qbA  = qtA * 64;
    const int qbB  = qtB * 64;
    const int nkt  = qtB + 1;            // compute work exactly 33 tiles/block

    __shared__ short Ks[2][64 * 64];     // 16 KB (dbuf)
    __shared__ short Vs[2][64 * 64];     // 16 KB (dbuf)
    __shared__ short Ps[4][16 * 64];     // 8 KB (per-wave P, XOR-swizzled)
    short* Pl = Ps[wave];

    // Q fragments for both subtiles; 1/sqrt(64)*log2(e) folded (p = exp2(s))
    const float scq = 0.125f * 1.44269504f;
    short8 qfA[2], qfB[2];
    {
        const float* qa = Q + ((size_t)((b * L_ + qbA + wave * 16 + l16) * H_ + h)) * D_;
        const float* qb = Q + ((size_t)((b * L_ + qbB + wave * 16 + l16) * H_ + h)) * D_;
#pragma unroll
        for (int kk = 0; kk < 2; ++kk) {
            const int d0 = kk * 32 + quad * 8;
            qfA[kk] = pack8(*(const float4*)(qa + d0), *(const float4*)(qa + d0 + 4), scq);
            qfB[kk] = pack8(*(const float4*)(qb + d0), *(const float4*)(qb + d0 + 4), scq);
        }
    }

    const short* Kg = Kb + (size_t)bh * L_ * D_;
    const short* Vg = Vt + (size_t)bh * D_ * L_;
    const int r8 = lane >> 3;                 // 0..7 row-within-8
    const int g8 = ((lane & 7) ^ r8) * 8;     // XOR-swizzled source chunk (shorts)

    f32x4 accA[4], accB[4];
#pragma unroll
    for (int c = 0; c < 4; ++c) {
        accA[c] = (f32x4){0.f, 0.f, 0.f, 0.f};
        accB[c] = (f32x4){0.f, 0.f, 0.f, 0.f};
    }
    float lsA[4] = {0.f, 0.f, 0.f, 0.f};
    float lsB[4] = {0.f, 0.f, 0.f, 0.f};

    auto stage = [&](int kt, int buf) {
#pragma unroll
        for (int half = 0; half < 2; ++half) {
            const int rbase = wave * 16 + half * 8;     // wave-uniform
            const int row   = rbase + r8;
            gld16(Kg + (size_t)(kt * 64 + row) * D_ + g8, &Ks[buf][rbase * 64]);
            gld16(Vg + (size_t)row * L_ + kt * 64 + g8, &Vs[buf][rbase * 64]);
        }
    };

    auto compute = [&](int kt, int buf, const short8* qf, int qt, f32x4* acc, float* ls) {
        // V fragments EARLY: Vs[buf] is barrier-guaranteed valid; the 8 b128
        // reads' latency hides under the 16 QK MFMAs instead of sitting on
        // the serial P-write -> PV path.
        short8 vbr[2][4];
#pragma unroll
        for (int ks = 0; ks < 2; ++ks) {
            const int cs = ((ks * 4 + quad) ^ (l16 & 7)) * 8;
#pragma unroll
            for (int cd = 0; cd < 4; ++cd)
                vbr[ks][cd] = *(short8*)&Vs[buf][(cd * 16 + l16) * 64 + cs];
        }
        f32x4 s[4];
#pragma unroll
        for (int ct = 0; ct < 4; ++ct) s[ct] = (f32x4){0.f, 0.f, 0.f, 0.f};
        __builtin_amdgcn_s_setprio(1);
#pragma unroll
        for (int kk = 0; kk < 2; ++kk) {
            const int cs = ((kk * 4 + quad) ^ (l16 & 7)) * 8;
#pragma unroll
            for (int ct = 0; ct < 4; ++ct) {
                short8 kf = *(short8*)&Ks[buf][(ct * 16 + l16) * 64 + cs];
                s[ct] = __builtin_amdgcn_mfma_f32_16x16x32_bf16(qf[kk], kf, s[ct], 0, 0, 0);
            }
        }
        __builtin_amdgcn_s_setprio(0);
        const bool diag = (kt == qt);
#pragma unroll
        for (int ct = 0; ct < 4; ++ct) {
#pragma unroll
            for (int r = 0; r < 4; ++r) {
                float sv = s[ct][r];
                if (diag && (ct * 16 + l16 > wave * 16 + quad * 4 + r)) sv = -1e30f;
                const float p = fast_exp2(sv);
                ls[r] += p;
                const int row = quad * 4 + r, col = ct * 16 + l16;
                Pl[row * 64 + ((col >> 3) ^ (row & 7)) * 8 + (col & 7)] = f2bf(p);
            }
        }
        short8 pa[2];
#pragma unroll
        for (int ks = 0; ks < 2; ++ks) {
            const int cs = ((ks * 4 + quad) ^ (l16 & 7)) * 8;
            pa[ks] = *(short8*)&Pl[l16 * 64 + cs];
        }
        __builtin_amdgcn_s_setprio(1);
#pragma unroll
        for (int ks = 0; ks < 2; ++ks) {
#pragma unroll
            for (int cd = 0; cd < 4; ++cd)
                acc[cd] = __builtin_amdgcn_mfma_f32_16x16x32_bf16(pa[ks], vbr[ks][cd], acc[cd], 0, 0, 0);
        }
        __builtin_amdgcn_s_setprio(0);
    };

    stage(0, 0);
    __syncthreads();
    for (int kt = 0; kt < nkt; ++kt) {
        const int buf = kt & 1;
        if (kt + 1 < nkt) stage(kt + 1, buf ^ 1);   // prefetch overlaps compute
        if (kt <= qtA) compute(kt, buf, qfA, qtA, accA, lsA);
        compute(kt, buf, qfB, qtB, accB, lsB);
        __syncthreads();                            // drains vmcnt: prefetch complete
    }

    auto epi = [&](int qbX, f32x4* acc, float* ls) {
#pragma unroll
        for (int r = 0; r < 4; ++r) {
            float t = ls[r];
#pragma unroll
            for (int off = 1; off < 16; off <<= 1) t += __shfl_xor(t, off);
            const float inv = 1.0f / t;
            float* orow = O + ((size_t)((b * L_ + qbX + wave * 16 + quad * 4 + r) * H_ + h)) * D_ + l16;
#pragma unroll
            for (int cd = 0; cd < 4; ++cd) orow[cd * 16] = acc[cd][r] * inv;
        }
    };
    epi(qbA, accA, lsA);
    epi(qbB, accB, lsB);
}

// ---------------- fallback (R2 kernel) if d_ws is too small ----------------
constexpr int KS = 72;
constexpr int VS = 72;
constexpr int PS = 68;

__global__ __launch_bounds__(256) void fa_fwd(
    const float* __restrict__ Q, const float* __restrict__ K,
    const float* __restrict__ V, float* __restrict__ O)
{
    const int tid  = threadIdx.x;
    const int wave = tid >> 6;
    const int lane = tid & 63;
    const int quad = lane >> 4;
    const int l16  = lane & 15;

    const int blk  = blockIdx.x;
    const int xcd  = blk & 7;
    const int slot = blk >> 3;
    const int bh   = xcd * 8 + (slot >> 5);
    const int qtile = 31 - (slot & 31);
    const int h = bh % H_;
    const int b = bh / H_;
    const int qbase = qtile * 64;
    const int qw    = qbase + wave * 16;

    __shared__ short Ks_s[64 * KS];
    __shared__ short Vt_s[64 * VS];
    __shared__ short Ps_s[4 * 16 * PS];
    short* Pl = &Ps_s[wave * 16 * PS];

    const float* qrow = Q + ((size_t)(b * L_ + qw + l16) * H_ + h) * D_;
    short8 qf[2];
#pragma unroll
    for (int kk = 0; kk < 2; ++kk) {
        const int d0 = kk * 32 + quad * 8;
        float4 f0 = *(const float4*)(qrow + d0);
        float4 f1 = *(const float4*)(qrow + d0 + 4);
        qf[kk] = pack8(f0, f1, 0.125f * 1.44269504f);
    }

    const int ksrow = tid >> 3;
    const int kscg  = (tid & 7) * 8;
    const int vs0   = (tid >> 4) * 4;
    const int vc0   = (tid & 15) * 4;

    f32x4 acc[4];
#pragma unroll
    for (int c = 0; c < 4; ++c) acc[c] = (f32x4){0.f, 0.f, 0.f, 0.f};
    float lsum[4] = {0.f, 0.f, 0.f, 0.f};

    const int nkt = qbase / 64 + 1;

    for (int kt = 0; kt < nkt; ++kt) {
        const int kbase = kt * 64;
        __syncthreads();
#pragma unroll
        for (int half = 0; half < 2; ++half) {
            const int row = ksrow + half * 32;
            const float* kr = K + ((size_t)(b * L_ + kbase + row) * H_ + h) * D_ + kscg;
            float4 f0 = *(const float4*)kr;
            float4 f1 = *(const float4*)(kr + 4);
            *(short8*)&Ks_s[row * KS + kscg] = pack8(f0, f1, 1.0f);
        }
        {
            const float* vb0 = V + ((size_t)(b * L_ + kbase + vs0) * H_ + h) * D_ + vc0;
            float4 r0 = *(const float4*)(vb0);
            float4 r1 = *(const float4*)(vb0 + H_ * D_);
            float4 r2 = *(const float4*)(vb0 + 2 * H_ * D_);
            float4 r3 = *(const float4*)(vb0 + 3 * H_ * D_);
            short4_t w;
            w[0] = f2bf(r0.x); w[1] = f2bf(r1.x); w[2] = f2bf(r2.x); w[3] = f2bf(r3.x);
            *(short4_t*)&Vt_s[(vc0 + 0) * VS + vs0] = w;
            w[0] = f2bf(r0.y); w[1] = f2bf(r1.y); w[2] = f2bf(r2.y); w[3] = f2bf(r3.y);
            *(short4_t*)&Vt_s[(vc0 + 1) * VS + vs0] = w;
            w[0] = f2bf(r0.z); w[1] = f2bf(r1.z); w[2] = f2bf(r2.z); w[3] = f2bf(r3.z);
            *(short4_t*)&Vt_s[(vc0 + 2) * VS + vs0] = w;
            w[0] = f2bf(r0.w); w[1] = f2bf(r1.w); w[2] = f2bf(r2.w); w[3] = f2bf(r3.w);
            *(short4_t*)&Vt_s[(vc0 + 3) * VS + vs0] = w;
        }
        __syncthreads();

        f32x4 s[4];
#pragma unroll
        for (int ct = 0; ct < 4; ++ct) s[ct] = (f32x4){0.f, 0.f, 0.f, 0.f};
#pragma unroll
        for (int kk = 0; kk < 2; ++kk) {
#pragma unroll
            for (int ct = 0; ct < 4; ++ct) {
                short8 kf = *(short8*)&Ks_s[(ct * 16 + l16) * KS + kk * 32 + quad * 8];
                s[ct] = __builtin_amdgcn_mfma_f32_16x16x32_bf16(qf[kk], kf, s[ct], 0, 0, 0);
            }
        }
        const bool diag = (kbase == qbase);
#pragma unroll
        for (int ct = 0; ct < 4; ++ct) {
#pragma unroll
            for (int r = 0; r < 4; ++r) {
                float sv = s[ct][r];
                if (diag && (ct * 16 + l16 > wave * 16 + quad * 4 + r)) sv = -1e30f;
                float p = fast_exp2(sv);
                lsum[r] += p;
                Pl[(quad * 4 + r) * PS + ct * 16 + l16] = f2bf(p);
            }
        }
#pragma unroll
        for (int ks = 0; ks < 2; ++ks) {
            short8 pa = *(short8*)&Pl[l16 * PS + ks * 32 + quad * 8];
#pragma unroll
            for (int c = 0; c < 4; ++c) {
                short8 vb = *(short8*)&Vt_s[(c * 16 + l16) * VS + ks * 32 + quad * 8];
                acc[c] = __builtin_amdgcn_mfma_f32_16x16x32_bf16(pa, vb, acc[c], 0, 0, 0);
            }
        }
    }

#pragma unroll
    for (int r = 0; r < 4; ++r) {
        float t = lsum[r];
#pragma unroll
        for (int off = 1; off < 16; off <<= 1) t += __shfl_xor(t, off);
        const float inv = 1.0f / t;
        const size_t row_off = ((size_t)(b * L_ + qw + quad * 4 + r) * H_ + h) * D_;
#pragma unroll
        for (int c = 0; c < 4; ++c)
            O[row_off + c * 16 + l16] = acc[c][r] * inv;
    }
}

extern "C" void kernel_launch(void* const* d_in, const int* in_sizes, int n_in,
                              void* d_out, int out_size, void* d_ws, size_t ws_size,
                              hipStream_t stream) {
    const float* Q = (const float*)d_in[0];
    const float* K = (const float*)d_in[1];
    const float* V = (const float*)d_in[2];
    float* O = (float*)d_out;
    const size_t need = (size_t)2 * BH_ * L_ * D_ * sizeof(short);
    if (ws_size >= need) {
        short* Kb = (short*)d_ws;
        short* Vt = Kb + (size_t)BH_ * L_ * D_;
        prepack<<<dim3(BH_ * (L_ / 64)), dim3(256), 0, stream>>>(K, V, Kb, Vt);
        fa_fwd2<<<dim3(1024), dim3(256), 0, stream>>>(Q, Kb, Vt, O);
    } else {
        fa_fwd<<<dim3(B_ * H_ * (L_ / 64)), dim3(256), 0, stream>>>(Q, K, V, O);
    }
}

// Round 5
// 190.171 us; speedup vs baseline: 1.2879x; 1.2879x over previous
//
#include <hip/hip_runtime.h>
#include <hip/hip_bf16.h>
#include <cstdint>
#include <cstddef>

#define B_ 4
#define L_ 2048
#define H_ 16
#define D_ 64
#define BH_ (B_*H_)

typedef __attribute__((ext_vector_type(8))) short short8;
typedef __attribute__((ext_vector_type(4))) short short4_t;
typedef __attribute__((ext_vector_type(4))) float f32x4;

__device__ __forceinline__ short f2bf(float x) {
    union { float f; unsigned u; } v; v.f = x;
    unsigned r = v.u + 0x7fffu + ((v.u >> 16) & 1u);
    return (short)(r >> 16);
}

// 2-op round-half-up bf16 (max err 0.5 ulp, same class as RNE) for the hot P path
__device__ __forceinline__ short f2bf_rh(float x) {
    union { float f; unsigned u; } v; v.f = x;
    return (short)((v.u + 0x8000u) >> 16);
}

__device__ __forceinline__ short8 pack8(float4 a, float4 b, float sc) {
    short8 t;
    t[0] = f2bf(a.x * sc); t[1] = f2bf(a.y * sc);
    t[2] = f2bf(a.z * sc); t[3] = f2bf(a.w * sc);
    t[4] = f2bf(b.x * sc); t[5] = f2bf(b.y * sc);
    t[6] = f2bf(b.z * sc); t[7] = f2bf(b.w * sc);
    return t;
}

__device__ __forceinline__ float fast_exp2(float x) {
#if __has_builtin(__builtin_amdgcn_exp2f)
    return __builtin_amdgcn_exp2f(x);
#else
    return exp2f(x);
#endif
}

// async global->LDS, 16B per lane; LDS dest is wave-uniform base + lane*16
__device__ __forceinline__ void gld16(const void* g, void* l) {
    __builtin_amdgcn_global_load_lds(
        (const __attribute__((address_space(1))) void*)g,
        (__attribute__((address_space(3))) void*)l, 16, 0, 0);
}

// ---------------- pre-pass: K -> bf16 [bh][s][d], V -> bf16 transposed [bh][d][s]
__global__ __launch_bounds__(256) void prepack(
    const float* __restrict__ K, const float* __restrict__ V,
    short* __restrict__ Kb, short* __restrict__ Vt)
{
    const int blk = blockIdx.x;          // 64 bh x 32 s-tiles
    const int bh  = blk >> 5;
    const int s0  = (blk & 31) * 64;
    const int b   = bh >> 4, h = bh & 15;
    const int t   = threadIdx.x;
    __shared__ short Ls[64 * 72];

#pragma unroll
    for (int half = 0; half < 2; ++half) {
        const int sl = (t >> 3) + half * 32;
        const int dc = (t & 7) * 8;
        const size_t src_off = ((size_t)((b * L_ + s0 + sl) * H_ + h)) * D_ + dc;
        float4 f0 = *(const float4*)(K + src_off);
        float4 f1 = *(const float4*)(K + src_off + 4);
        *(short8*)&Kb[((size_t)bh * L_ + s0 + sl) * D_ + dc] = pack8(f0, f1, 1.0f);
        float4 g0 = *(const float4*)(V + src_off);
        float4 g1 = *(const float4*)(V + src_off + 4);
        *(short8*)&Ls[sl * 72 + dc] = pack8(g0, g1, 1.0f);
    }
    __syncthreads();
    const int d  = t >> 2;
    const int sc = (t & 3) * 16;
    short8 o0, o1;
#pragma unroll
    for (int j = 0; j < 8; ++j) o0[j] = Ls[(sc + j) * 72 + d];
#pragma unroll
    for (int j = 0; j < 8; ++j) o1[j] = Ls[(sc + 8 + j) * 72 + d];
    short* dst = Vt + ((size_t)bh * D_ + d) * L_ + s0 + sc;
    *(short8*)dst = o0;
    *(short8*)(dst + 8) = o1;
}

// ---------------- main kernel: paired q-tiles (i, 31-i), dbuf global_load_lds staging
// R5 = R0 exact structure + diag-split (mask ops only on the 1/33 diagonal tile)
//      + 2-op round-half-up P conversion + setprio around MFMA clusters.
//      NO extra live registers across MFMA clusters (R4 spill lesson).
__global__ __launch_bounds__(256, 4) void fa_fwd2(
    const float* __restrict__ Q, const short* __restrict__ Kb,
    const short* __restrict__ Vt, float* __restrict__ O)
{
    const int tid  = threadIdx.x;
    const int wave = tid >> 6;
    const int lane = tid & 63;
    const int quad = lane >> 4;
    const int l16  = lane & 15;

    const int blk  = blockIdx.x;
    const int xcd  = blk & 7;
    const int slot = blk >> 3;           // 0..127
    const int bh   = xcd * 8 + (slot & 7);
    const int ip   = slot >> 3;          // 0..15 pair index (mixed across a CU's blocks)
    const int b    = bh >> 4;
    const int h    = bh & 15;
    const int qtA  = ip;                 // short q-tile
    const int qtB  = 31 - ip;            // long q-tile
    const int qbA  = qtA * 64;
    const int qbB  = qtB * 64;
    const int nkt  = qtB + 1;            // compute work exactly 33 tiles/block

    __shared__ short Ks[2][64 * 64];     // 16 KB (dbuf)
    __shared__ short Vs[2][64 * 64];     // 16 KB (dbuf)
    __shared__ short Ps[4][16 * 64];     // 8 KB (per-wave P, XOR-swizzled)
    short* Pl = Ps[wave];

    // Q fragments for both subtiles; 1/sqrt(64)*log2(e) folded (p = exp2(s))
    const float scq = 0.125f * 1.44269504f;
    short8 qfA[2], qfB[2];
    {
        const float* qa = Q + ((size_t)((b * L_ + qbA + wave * 16 + l16) * H_ + h)) * D_;
        const float* qb = Q + ((size_t)((b * L_ + qbB + wave * 16 + l16) * H_ + h)) * D_;
#pragma unroll
        for (int kk = 0; kk < 2; ++kk) {
            const int d0 = kk * 32 + quad * 8;
            qfA[kk] = pack8(*(const float4*)(qa + d0), *(const float4*)(qa + d0 + 4), scq);
            qfB[kk] = pack8(*(const float4*)(qb + d0), *(const float4*)(qb + d0 + 4), scq);
        }
    }

    const short* Kg = Kb + (size_t)bh * L_ * D_;
    const short* Vg = Vt + (size_t)bh * D_ * L_;
    const int r8 = lane >> 3;                 // 0..7 row-within-8
    const int g8 = ((lane & 7) ^ r8) * 8;     // XOR-swizzled source chunk (shorts)

    f32x4 accA[4], accB[4];
#pragma unroll
    for (int c = 0; c < 4; ++c) {
        accA[c] = (f32x4){0.f, 0.f, 0.f, 0.f};
        accB[c] = (f32x4){0.f, 0.f, 0.f, 0.f};
    }
    float lsA[4] = {0.f, 0.f, 0.f, 0.f};
    float lsB[4] = {0.f, 0.f, 0.f, 0.f};

    auto stage = [&](int kt, int buf) {
#pragma unroll
        for (int half = 0; half < 2; ++half) {
            const int rbase = wave * 16 + half * 8;     // wave-uniform
            const int row   = rbase + r8;
            gld16(Kg + (size_t)(kt * 64 + row) * D_ + g8, &Ks[buf][rbase * 64]);
            gld16(Vg + (size_t)row * L_ + kt * 64 + g8, &Vs[buf][rbase * 64]);
        }
    };

    auto compute = [&](int kt, int buf, const short8* qf, int qt, f32x4* acc, float* ls) {
        f32x4 s[4];
#pragma unroll
        for (int ct = 0; ct < 4; ++ct) s[ct] = (f32x4){0.f, 0.f, 0.f, 0.f};
        __builtin_amdgcn_s_setprio(1);
#pragma unroll
        for (int kk = 0; kk < 2; ++kk) {
            const int cs = ((kk * 4 + quad) ^ (l16 & 7)) * 8;
#pragma unroll
            for (int ct = 0; ct < 4; ++ct) {
                short8 kf = *(short8*)&Ks[buf][(ct * 16 + l16) * 64 + cs];
                s[ct] = __builtin_amdgcn_mfma_f32_16x16x32_bf16(qf[kk], kf, s[ct], 0, 0, 0);
            }
        }
        __builtin_amdgcn_s_setprio(0);
        // softmax: uniform branch keeps mask ops out of 32/33 tiles
        if (kt == qt) {
#pragma unroll
            for (int ct = 0; ct < 4; ++ct) {
#pragma unroll
                for (int r = 0; r < 4; ++r) {
                    float sv = s[ct][r];
                    if (ct * 16 + l16 > wave * 16 + quad * 4 + r) sv = -1e30f;
                    const float p = fast_exp2(sv);
                    ls[r] += p;
                    const int row = quad * 4 + r, col = ct * 16 + l16;
                    Pl[row * 64 + ((col >> 3) ^ (row & 7)) * 8 + (col & 7)] = f2bf_rh(p);
                }
            }
        } else {
#pragma unroll
            for (int ct = 0; ct < 4; ++ct) {
#pragma unroll
                for (int r = 0; r < 4; ++r) {
                    const float p = fast_exp2(s[ct][r]);
                    ls[r] += p;
                    const int row = quad * 4 + r, col = ct * 16 + l16;
                    Pl[row * 64 + ((col >> 3) ^ (row & 7)) * 8 + (col & 7)] = f2bf_rh(p);
                }
            }
        }
        __builtin_amdgcn_s_setprio(1);
#pragma unroll
        for (int ks = 0; ks < 2; ++ks) {
            const int cs = ((ks * 4 + quad) ^ (l16 & 7)) * 8;
            short8 pa = *(short8*)&Pl[l16 * 64 + cs];
#pragma unroll
            for (int cd = 0; cd < 4; ++cd) {
                short8 vb = *(short8*)&Vs[buf][(cd * 16 + l16) * 64 + cs];
                acc[cd] = __builtin_amdgcn_mfma_f32_16x16x32_bf16(pa, vb, acc[cd], 0, 0, 0);
            }
        }
        __builtin_amdgcn_s_setprio(0);
    };

    stage(0, 0);
    __syncthreads();
    for (int kt = 0; kt < nkt; ++kt) {
        const int buf = kt & 1;
        if (kt + 1 < nkt) stage(kt + 1, buf ^ 1);   // prefetch overlaps compute
        if (kt <= qtA) compute(kt, buf, qfA, qtA, accA, lsA);
        compute(kt, buf, qfB, qtB, accB, lsB);
        __syncthreads();                            // drains vmcnt: prefetch complete
    }

    auto epi = [&](int qbX, f32x4* acc, float* ls) {
#pragma unroll
        for (int r = 0; r < 4; ++r) {
            float t = ls[r];
#pragma unroll
            for (int off = 1; off < 16; off <<= 1) t += __shfl_xor(t, off);
            const float inv = 1.0f / t;
            float* orow = O + ((size_t)((b * L_ + qbX + wave * 16 + quad * 4 + r) * H_ + h)) * D_ + l16;
#pragma unroll
            for (int cd = 0; cd < 4; ++cd) orow[cd * 16] = acc[cd][r] * inv;
        }
    };
    epi(qbA, accA, lsA);
    epi(qbB, accB, lsB);
}

// ---------------- fallback (R2 kernel) if d_ws is too small ----------------
constexpr int KS = 72;
constexpr int VS = 72;
constexpr int PS = 68;

__global__ __launch_bounds__(256) void fa_fwd(
    const float* __restrict__ Q, const float* __restrict__ K,
    const float* __restrict__ V, float* __restrict__ O)
{
    const int tid  = threadIdx.x;
    const int wave = tid >> 6;
    const int lane = tid & 63;
    const int quad = lane >> 4;
    const int l16  = lane & 15;

    const int blk  = blockIdx.x;
    const int xcd  = blk & 7;
    const int slot = blk >> 3;
    const int bh   = xcd * 8 + (slot >> 5);
    const int qtile = 31 - (slot & 31);
    const int h = bh % H_;
    const int b = bh / H_;
    const int qbase = qtile * 64;
    const int qw    = qbase + wave * 16;

    __shared__ short Ks_s[64 * KS];
    __shared__ short Vt_s[64 * VS];
    __shared__ short Ps_s[4 * 16 * PS];
    short* Pl = &Ps_s[wave * 16 * PS];

    const float* qrow = Q + ((size_t)(b * L_ + qw + l16) * H_ + h) * D_;
    short8 qf[2];
#pragma unroll
    for (int kk = 0; kk < 2; ++kk) {
        const int d0 = kk * 32 + quad * 8;
        float4 f0 = *(const float4*)(qrow + d0);
        float4 f1 = *(const float4*)(qrow + d0 + 4);
        qf[kk] = pack8(f0, f1, 0.125f * 1.44269504f);
    }

    const int ksrow = tid >> 3;
    const int kscg  = (tid & 7) * 8;
    const int vs0   = (tid >> 4) * 4;
    const int vc0   = (tid & 15) * 4;

    f32x4 acc[4];
#pragma unroll
    for (int c = 0; c < 4; ++c) acc[c] = (f32x4){0.f, 0.f, 0.f, 0.f};
    float lsum[4] = {0.f, 0.f, 0.f, 0.f};

    const int nkt = qbase / 64 + 1;

    for (int kt = 0; kt < nkt; ++kt) {
        const int kbase = kt * 64;
        __syncthreads();
#pragma unroll
        for (int half = 0; half < 2; ++half) {
            const int row = ksrow + half * 32;
            const float* kr = K + ((size_t)(b * L_ + kbase + row) * H_ + h) * D_ + kscg;
            float4 f0 = *(const float4*)kr;
            float4 f1 = *(const float4*)(kr + 4);
            *(short8*)&Ks_s[row * KS + kscg] = pack8(f0, f1, 1.0f);
        }
        {
            const float* vb0 = V + ((size_t)(b * L_ + kbase + vs0) * H_ + h) * D_ + vc0;
            float4 r0 = *(const float4*)(vb0);
            float4 r1 = *(const float4*)(vb0 + H_ * D_);
            float4 r2 = *(const float4*)(vb0 + 2 * H_ * D_);
            float4 r3 = *(const float4*)(vb0 + 3 * H_ * D_);
            short4_t w;
            w[0] = f2bf(r0.x); w[1] = f2bf(r1.x); w[2] = f2bf(r2.x); w[3] = f2bf(r3.x);
            *(short4_t*)&Vt_s[(vc0 + 0) * VS + vs0] = w;
            w[0] = f2bf(r0.y); w[1] = f2bf(r1.y); w[2] = f2bf(r2.y); w[3] = f2bf(r3.y);
            *(short4_t*)&Vt_s[(vc0 + 1) * VS + vs0] = w;
            w[0] = f2bf(r0.z); w[1] = f2bf(r1.z); w[2] = f2bf(r2.z); w[3] = f2bf(r3.z);
            *(short4_t*)&Vt_s[(vc0 + 2) * VS + vs0] = w;
            w[0] = f2bf(r0.w); w[1] = f2bf(r1.w); w[2] = f2bf(r2.w); w[3] = f2bf(r3.w);
            *(short4_t*)&Vt_s[(vc0 + 3) * VS + vs0] = w;
        }
        __syncthreads();

        f32x4 s[4];
#pragma unroll
        for (int ct = 0; ct < 4; ++ct) s[ct] = (f32x4){0.f, 0.f, 0.f, 0.f};
#pragma unroll
        for (int kk = 0; kk < 2; ++kk) {
#pragma unroll
            for (int ct = 0; ct < 4; ++ct) {
                short8 kf = *(short8*)&Ks_s[(ct * 16 + l16) * KS + kk * 32 + quad * 8];
                s[ct] = __builtin_amdgcn_mfma_f32_16x16x32_bf16(qf[kk], kf, s[ct], 0, 0, 0);
            }
        }
        const bool diag = (kbase == qbase);
#pragma unroll
        for (int ct = 0; ct < 4; ++ct) {
#pragma unroll
            for (int r = 0; r < 4; ++r) {
                float sv = s[ct][r];
                if (diag && (ct * 16 + l16 > wave * 16 + quad * 4 + r)) sv = -1e30f;
                float p = fast_exp2(sv);
                lsum[r] += p;
                Pl[(quad * 4 + r) * PS + ct * 16 + l16] = f2bf(p);
            }
        }
#pragma unroll
        for (int ks = 0; ks < 2; ++ks) {
            short8 pa = *(short8*)&Pl[l16 * PS + ks * 32 + quad * 8];
#pragma unroll
            for (int c = 0; c < 4; ++c) {
                short8 vb = *(short8*)&Vt_s[(c * 16 + l16) * VS + ks * 32 + quad * 8];
                acc[c] = __builtin_amdgcn_mfma_f32_16x16x32_bf16(pa, vb, acc[c], 0, 0, 0);
            }
        }
    }

#pragma unroll
    for (int r = 0; r < 4; ++r) {
        float t = lsum[r];
#pragma unroll
        for (int off = 1; off < 16; off <<= 1) t += __shfl_xor(t, off);
        const float inv = 1.0f / t;
        const size_t row_off = ((size_t)(b * L_ + qw + quad * 4 + r) * H_ + h) * D_;
#pragma unroll
        for (int c = 0; c < 4; ++c)
            O[row_off + c * 16 + l16] = acc[c][r] * inv;
    }
}

extern "C" void kernel_launch(void* const* d_in, const int* in_sizes, int n_in,
                              void* d_out, int out_size, void* d_ws, size_t ws_size,
                              hipStream_t stream) {
    const float* Q = (const float*)d_in[0];
    const float* K = (const float*)d_in[1];
    const float* V = (const float*)d_in[2];
    float* O = (float*)d_out;
    const size_t need = (size_t)2 * BH_ * L_ * D_ * sizeof(short);
    if (ws_size >= need) {
        short* Kb = (short*)d_ws;
        short* Vt = Kb + (size_t)BH_ * L_ * D_;
        prepack<<<dim3(BH_ * (L_ / 64)), dim3(256), 0, stream>>>(K, V, Kb, Vt);
        fa_fwd2<<<dim3(1024), dim3(256), 0, stream>>>(Q, Kb, Vt, O);
    } else {
        fa_fwd<<<dim3(B_ * H_ * (L_ / 64)), dim3(256), 0, stream>>>(Q, K, V, O);
    }
}